// Round 7
// baseline (9191.144 us; speedup 1.0000x reference)
//
#include <hip/hip_runtime.h>
#include <stdint.h>

// RNN_6725918786207: 2-layer tanh RNN. B=64, T=512, D_IN=64, D_MODEL=512, D_OUT=64.
// Round 7: recurrence split 4 ways in N across 4 WGs per batch-group (64 WGs, 4x CUs
// of round 6). Per step each WG computes 128 cols of h_t, publishes them to a fresh
// global slot Hlay[t+1], then release-stores a per-WG flag; consumers acquire-poll
// the 3 partner flags. No AGPR tricks: per-wave B = 2 nt x 16 kt = 128 arch VGPRs.
// Hlay doubles as the layer's H output (GEMMs read the [t+1][bg][b&3][col] layout).
// R6 lesson: per-CU MFMA issue is the floor; only spreading cols across CUs helps.

typedef unsigned int u32;
typedef unsigned short u16;
typedef _Float16 f16;
typedef _Float16 v8h __attribute__((ext_vector_type(8)));
typedef float    v4f __attribute__((ext_vector_type(4)));

#define T_STEPS 512
#define DM 512
#define BATCH 64

// ---------- small helpers ----------
__device__ __forceinline__ float f16bits(u16 s) {
    f16 h; __builtin_memcpy(&h, &s, 2); return (float)h;
}
__device__ __forceinline__ u32 packh2(float lo, float hi) {
    f16 a = (f16)lo, b = (f16)hi; u16 ua, ub;
    __builtin_memcpy(&ua, &a, 2); __builtin_memcpy(&ub, &b, 2);
    return (u32)ua | ((u32)ub << 16);
}
__device__ __forceinline__ float tanh_fast(float z) {
    float e = __expf(2.0f * z);
    return 1.0f - 2.0f / (e + 1.0f);
}

// ---------- prep kernels ----------
__global__ void k_cast_f16(const float* __restrict__ src, f16* __restrict__ dst, int n) {
    int i = blockIdx.x * blockDim.x + threadIdx.x;
    if (i < n) dst[i] = (f16)src[i];
}

// Whh [512][512] fp32 (k-major rows) -> fragment-ordered f16:
// Wf[kt][nt][lane][j] = W[kt*32 + (lane>>4)*8 + j][nt*16 + (lane&15)]
__global__ void k_pack_frag(const float* __restrict__ W, uint4* __restrict__ Wf) {
    int i = blockIdx.x * blockDim.x + threadIdx.x;   // 32768 = 16*32*64
    int kt = i >> 11, nt = (i >> 6) & 31, l = i & 63;
    int col = nt * 16 + (l & 15);
    int k0 = kt * 32 + (l >> 4) * 8;
    f16 v[8];
    #pragma unroll
    for (int j = 0; j < 8; ++j) v[j] = (f16)W[(size_t)(k0 + j) * DM + col];
    uint4 o; __builtin_memcpy(&o, v, 16);
    Wf[i] = o;
}

// src fp32 [R][C] -> dst fp16 [C][R]
__global__ void k_transpose_f16(const float* __restrict__ src, f16* __restrict__ dst, int R, int C) {
    int i = blockIdx.x * blockDim.x + threadIdx.x;
    if (i < R * C) { int r = i / C, c = i % C; dst[c * R + r] = (f16)src[r * C + c]; }
}

__global__ void k_bias_sum(const float* a0, const float* b0, float* o0,
                           const float* a1, const float* b1, float* o1) {
    int i = blockIdx.x * blockDim.x + threadIdx.x;
    if (i < DM) { o0[i] = a0[i] + b0[i]; o1[i] = a1[i] + b1[i]; }
}

// ---------- X-producing GEMM: tile mb = t, in-tile row = batch b.
// amode 0: A row-major [b][t][K] (D16). amode 1: A = Hlay f16 [t+1][bg][b&3][512].
// Output Xt packed: uint2 at (bg*512 + t)*512 + col holding batches r=0..3 f16.
__global__ __launch_bounds__(256) void k_gemm_x(const f16* __restrict__ A, const f16* __restrict__ BT,
                                                f16* __restrict__ Xt, const float* __restrict__ bias,
                                                int K, int amode) {
    __shared__ f16 As[64][40];
    __shared__ f16 Bs[64][40];
    int tid = threadIdx.x;
    int mb = blockIdx.x, nb = blockIdx.y;   // mb = t (0..511), nb = n-block (0..7)
    int l = tid & 63, w = tid >> 6;
    int q = l >> 4, mr = l & 15;
    int sr = tid >> 2;                      // = batch b for A staging
    int ko = (tid & 3) * 8;
    size_t aoff = (amode == 0)
        ? ((size_t)sr * T_STEPS + mb) * K + ko
        : ((size_t)(mb + 1) * 32768 + (size_t)(sr >> 2) * 2048 + (size_t)(sr & 3) * 512 + ko);
    const f16* gA = A + aoff;
    const f16* gB = BT + (size_t)(nb * 64 + sr) * K + ko;

    v4f acc[4];
    #pragma unroll
    for (int nt = 0; nt < 4; ++nt) acc[nt] = (v4f){0.f, 0.f, 0.f, 0.f};

    for (int kt = 0; kt < K; kt += 32) {
        *(uint4*)&As[sr][ko] = *(const uint4*)(gA + kt);
        *(uint4*)&Bs[sr][ko] = *(const uint4*)(gB + kt);
        __syncthreads();
        v8h a = *(const v8h*)&As[w * 16 + mr][q * 8];
        #pragma unroll
        for (int nt = 0; nt < 4; ++nt) {
            v8h b = *(const v8h*)&Bs[nt * 16 + mr][q * 8];
            acc[nt] = __builtin_amdgcn_mfma_f32_16x16x32_f16(a, b, acc[nt], 0, 0, 0);
        }
        __syncthreads();
    }

    uint2* Xo = (uint2*)Xt;
    int grp = w * 4 + q;                    // = b>>2
    #pragma unroll
    for (int nt = 0; nt < 4; ++nt) {
        int col = nb * 64 + nt * 16 + mr;
        float bv = bias[col];
        u32 p01 = packh2(acc[nt][0] + bv, acc[nt][1] + bv);
        u32 p23 = packh2(acc[nt][2] + bv, acc[nt][3] + bv);
        Xo[((size_t)grp * T_STEPS + mb) * DM + col] = make_uint2(p01, p23);
    }
}

// ---------- output GEMM: A = Hlay (f16 [t+1][bg][b&3][512]), rows of d_out = b*T+t.
__global__ __launch_bounds__(256) void k_gemm_out(const f16* __restrict__ Hlay, const f16* __restrict__ BT,
                                                  float* __restrict__ Cout, const float* __restrict__ bias) {
    const int K = 512, N = 64;
    __shared__ f16 As[64][40];
    __shared__ f16 Bs[64][40];
    int tid = threadIdx.x;
    int mb = blockIdx.x;                    // 64-row tile of d_out (rows = b*512+t)
    int l = tid & 63, w = tid >> 6;
    int q = l >> 4, mr = l & 15;
    int sr = tid >> 2;
    int ko = (tid & 3) * 8;
    int row = mb * 64 + sr, b = row >> 9, t = row & 511;
    const f16* gA = Hlay + (size_t)(t + 1) * 32768 + (size_t)(b >> 2) * 2048 + (size_t)(b & 3) * 512 + ko;
    const f16* gB = BT + (size_t)sr * K + ko;

    v4f acc[4];
    #pragma unroll
    for (int nt = 0; nt < 4; ++nt) acc[nt] = (v4f){0.f, 0.f, 0.f, 0.f};

    for (int kt = 0; kt < K; kt += 32) {
        *(uint4*)&As[sr][ko] = *(const uint4*)(gA + kt);
        *(uint4*)&Bs[sr][ko] = *(const uint4*)(gB + kt);
        __syncthreads();
        v8h a = *(const v8h*)&As[w * 16 + mr][q * 8];
        #pragma unroll
        for (int nt = 0; nt < 4; ++nt) {
            v8h b = *(const v8h*)&Bs[nt * 16 + mr][q * 8];
            acc[nt] = __builtin_amdgcn_mfma_f32_16x16x32_f16(a, b, acc[nt], 0, 0, 0);
        }
        __syncthreads();
    }

    int row0 = mb * 64 + w * 16 + q * 4;
    #pragma unroll
    for (int nt = 0; nt < 4; ++nt) {
        int col = nt * 16 + mr;
        float bv = bias[col];
        #pragma unroll
        for (int r = 0; r < 4; ++r)
            Cout[(size_t)(row0 + r) * N + col] = acc[nt][r] + bv;
    }
}

// ---------- split recurrence ----------
// 64 WGs x 256 threads. blk = bg + 16*part: bg = batch-group (4 batches), part owns
// cols [part*128, part*128+128). Wave w owns n-tiles nt0 = part*8+w*2, nt0+1.
// Per step: poll 3 partner flags (acquire) -> read full h_{t-1} fragments from
// Hlay[t] (global, fresh addresses) -> 32 MFMA -> tanh -> store 128 cols to
// Hlay[t+1] -> __syncthreads -> tid0 release-stores flags[blk] = t+1.
__global__ __launch_bounds__(256) void k_rnn4(const uint4* __restrict__ Wf,
                                              const uint2* __restrict__ Xt,
                                              f16* __restrict__ Hlay,
                                              u32* __restrict__ flags) {
    int blk = blockIdx.x;
    int bg = blk & 15, part = blk >> 4;
    int tid = threadIdx.x, w = tid >> 6, l = tid & 63;
    int l15 = l & 15, q = l >> 4, b3 = l & 3;
    int nt0 = part * 8 + w * 2;

    const v8h* WfH = (const v8h*)Wf;
    v8h breg[2][16];
    #pragma unroll
    for (int j = 0; j < 2; ++j)
        #pragma unroll
        for (int kt = 0; kt < 16; ++kt) {
            breg[j][kt] = WfH[(size_t)(kt * 32 + nt0 + j) * 64 + l];
            asm volatile("" : "+v"(breg[j][kt]));
        }

    int col0 = nt0 * 16 + l15, col1 = col0 + 16;
    const char* Xb = (const char*)(Xt + (size_t)bg * T_STEPS * DM);
    // prefetch x for t=0
    u16 xc0 = *(const u16*)(Xb + ((size_t)0 * DM + col0) * 8 + q * 2);
    u16 xc1 = *(const u16*)(Xb + ((size_t)0 * DM + col1) * 8 + q * 2);

    #pragma unroll 1
    for (int t = 0; t < T_STEPS; ++t) {
        // keep B resident (loop-carried opaque defs; R6-proven pattern)
        #pragma unroll
        for (int j = 0; j < 2; ++j)
            #pragma unroll
            for (int kt = 0; kt < 16; ++kt)
                asm volatile("" : "+v"(breg[j][kt]));

        if (t) {
            #pragma unroll
            for (int p = 0; p < 4; ++p) {
                if (p == part) continue;
                const u32* fp = &flags[bg + 16 * p];
                while (__hip_atomic_load(fp, __ATOMIC_ACQUIRE, __HIP_MEMORY_SCOPE_AGENT) < (u32)t) { }
            }
        }

        // prefetch x for t+1 (hidden behind this step's MFMA + next poll)
        int tn = (t + 1 < T_STEPS) ? t + 1 : t;
        u16 xn0 = *(const u16*)(Xb + ((size_t)tn * DM + col0) * 8 + q * 2);
        u16 xn1 = *(const u16*)(Xb + ((size_t)tn * DM + col1) * 8 + q * 2);

        // A fragments of h_{t-1}: Hlay slot t, batch b3, k = kt*32 + q*8 .. +8
        const f16* hrow = Hlay + (size_t)t * 32768 + (size_t)bg * 2048 + (size_t)b3 * 512 + q * 8;
        v8h a[16];
        #pragma unroll
        for (int kt = 0; kt < 16; ++kt) a[kt] = *(const v8h*)(hrow + kt * 32);

        v4f acc[2][2];
        acc[0][0] = (v4f){0.f,0.f,0.f,0.f}; acc[0][1] = (v4f){0.f,0.f,0.f,0.f};
        acc[1][0] = (v4f){0.f,0.f,0.f,0.f}; acc[1][1] = (v4f){0.f,0.f,0.f,0.f};
        #pragma unroll
        for (int kt = 0; kt < 16; ++kt) {
            acc[0][kt & 1] = __builtin_amdgcn_mfma_f32_16x16x32_f16(a[kt], breg[0][kt], acc[0][kt & 1], 0, 0, 0);
            acc[1][kt & 1] = __builtin_amdgcn_mfma_f32_16x16x32_f16(a[kt], breg[1][kt], acc[1][kt & 1], 0, 0, 0);
        }
        v4f C0 = acc[0][0] + acc[0][1];
        v4f C1 = acc[1][0] + acc[1][1];

        // quad q writes batch q (C/D row 5q has batch 5q&3 == q); value = C[q]
        float c0 = (q & 2) ? ((q & 1) ? C0[3] : C0[2]) : ((q & 1) ? C0[1] : C0[0]);
        float c1 = (q & 2) ? ((q & 1) ? C1[3] : C1[2]) : ((q & 1) ? C1[1] : C1[0]);
        f16 h0 = (f16)tanh_fast(c0 + f16bits(xc0));
        f16 h1 = (f16)tanh_fast(c1 + f16bits(xc1));
        f16* hw = Hlay + (size_t)(t + 1) * 32768 + (size_t)bg * 2048 + (size_t)q * 512;
        hw[col0] = h0;
        hw[col1] = h1;

        __syncthreads();                     // all waves' stores drained (vmcnt 0)
        if (tid == 0)
            __hip_atomic_store(&flags[blk], (u32)(t + 1), __ATOMIC_RELEASE, __HIP_MEMORY_SCOPE_AGENT);
        xc0 = xn0; xc1 = xn1;
    }
}

// ---------- launch ----------
extern "C" void kernel_launch(void* const* d_in, const int* in_sizes, int n_in,
                              void* d_out, int out_size, void* d_ws, size_t ws_size,
                              hipStream_t stream) {
    (void)in_sizes; (void)n_in; (void)out_size; (void)ws_size;
    const float* data = (const float*)d_in[0];
    const float* Wih0 = (const float*)d_in[1];
    const float* bih0 = (const float*)d_in[2];
    const float* Whh0 = (const float*)d_in[3];
    const float* bhh0 = (const float*)d_in[4];
    const float* Wih1 = (const float*)d_in[5];
    const float* bih1 = (const float*)d_in[6];
    const float* Whh1 = (const float*)d_in[7];
    const float* bhh1 = (const float*)d_in[8];
    const float* Wout = (const float*)d_in[9];
    const float* bout = (const float*)d_in[10];

    char* ws = (char*)d_ws;
    // workspace layout (bytes); total = 102,502,912
    f16*   Xt    = (f16*)(ws + 0);                   // packed X [16][512][512] uint2 = 33.5 MB
    f16*   H0lay = (f16*)(ws + 33554432);            // [513][16][4][512] f16 = 33.6 MB (slot 0 zeros)
    f16*   H1lay = (f16*)(ws + 67174400);            // [513][16][4][512] f16
    f16*   D16   = (f16*)(ws + 67174400 + 65536);    // 4 MB, overlaps H1lay slots>=1 (dead before k_rnn4 #2)
    uint4* Wf0   = (uint4*)(ws + 100794368);         // frag-ordered Whh0 (512 KB)
    uint4* Wf1   = (uint4*)(ws + 101318656);         // frag-ordered Whh1 (512 KB)
    f16*   WT0   = (f16*)(ws + 101842944);           // Wih0^T [512][64]
    f16*   WT1   = (f16*)(ws + 101908480);           // Wih1^T [512][512]
    f16*   WoT   = (f16*)(ws + 102432768);           // Wout^T [64][512]
    float* bias0 = (float*)(ws + 102498304);
    float* bias1 = (float*)(ws + 102500352);
    u32*   flags = (u32*)(ws + 102502400);           // [2][64] step flags

    // zero flags and the h_{-1}=0 slots (ws is poisoned 0xAA before every launch)
    hipMemsetAsync(flags, 0, 512, stream);
    hipMemsetAsync(H0lay, 0, 65536, stream);
    hipMemsetAsync(H1lay, 0, 65536, stream);

    // prep
    k_cast_f16<<<8192, 256, 0, stream>>>(data, D16, BATCH * T_STEPS * 64);
    k_pack_frag<<<128, 256, 0, stream>>>(Whh0, Wf0);
    k_pack_frag<<<128, 256, 0, stream>>>(Whh1, Wf1);
    k_transpose_f16<<<128, 256, 0, stream>>>(Wih0, WT0, 64, 512);
    k_transpose_f16<<<1024, 256, 0, stream>>>(Wih1, WT1, 512, 512);
    k_transpose_f16<<<128, 256, 0, stream>>>(Wout, WoT, 512, 64);
    k_bias_sum<<<2, 256, 0, stream>>>(bih0, bhh0, bias0, bih1, bhh1, bias1);

    dim3 gX(512, 8);
    // X0 = data @ Wih0 + bias0  -> Xt packed
    k_gemm_x<<<gX, 256, 0, stream>>>(D16, WT0, Xt, bias0, 64, 0);
    // layer-0 recurrence (4-way split)
    k_rnn4<<<64, 256, 0, stream>>>(Wf0, (const uint2*)Xt, H0lay, flags);
    // X1 = H0 @ Wih1 + bias1 -> Xt packed
    k_gemm_x<<<gX, 256, 0, stream>>>(H0lay, WT1, Xt, bias1, 512, 1);
    // layer-1 recurrence
    k_rnn4<<<64, 256, 0, stream>>>(Wf1, (const uint2*)Xt, H1lay, flags + 64);
    // OUT = H1 @ Wout + bout -> fp32 d_out
    k_gemm_out<<<512, 256, 0, stream>>>(H1lay, WoT, (float*)d_out, bout);
}